// Round 2
// baseline (877.712 us; speedup 1.0000x reference)
//
#include <hip/hip_runtime.h>
#include <hip/hip_bf16.h>
#include <math.h>

#define DDIM 300
#define PFN  12
#define LFN  8
#define ICH  21
#define TPB  128
#define SPB  32          // samples per block (4 threads each)

// LDS element strides (per sample)
#define FEAT_PSTR 22                 // bf16 per position (21 used + 1 pad -> 4B align)
#define FEAT_STR  (9 * FEAT_PSTR)    // 198 bf16 = 99 dwords (odd -> bank spread)
#define POOL_STR  84                 // dwords (80 used; 84 -> 2-way max on b128)
#define X30_STR   36                 // dwords (30 used; 4s bank spread, 16B align)
#define H_STR     120                // dwords
// Overlay layout (bytes):
//   region A @0     : feat  (32*396 = 12672)  gather -> conv1
//   region A @0     : pooled(32*336 = 10752)  pool   -> conv2
//   region A @0     : h     (32*480 = 15360)  fc1    -> fc2
//   region B @15360 : x30   (32*144 =  4608)  conv2  -> fc1
#define X30_OFF   15360
#define LDS_BYTES (15360 + SPB * X30_STR * 4)   // 19968 B -> 8 blocks/CU = 156KB

__device__ __forceinline__ float lrelu(float v) { return v > 0.0f ? v : 0.2f * v; }

__device__ __forceinline__ unsigned short f2bf(float f) {
    return __builtin_bit_cast(unsigned short, __float2bfloat16(f));
}
__device__ __forceinline__ float bf2f(unsigned short u) {
    return __builtin_bit_cast(float, (unsigned int)u << 16);
}

__launch_bounds__(TPB, 4)
__global__ void disc_kernel(
    const int* __restrict__ state, const int* __restrict__ des,
    const int* __restrict__ act,
    const int* __restrict__ asp_g,   // (S,9)
    const int* __restrict__ pmp_g,   // (S,9)
    const float* __restrict__ path_feature,  // (S,D,12)
    const float* __restrict__ link_feature,  // (S,8)
    const float* __restrict__ w1, const float* __restrict__ b1,   // (20,21,3,3)
    const float* __restrict__ w2, const float* __restrict__ b2,   // (30,20,2,2)
    const float* __restrict__ fw1, const float* __restrict__ fb1, // (120,38)
    const float* __restrict__ fw2, const float* __restrict__ fb2, // (84,120)
    const float* __restrict__ fw3, const float* __restrict__ fb3, // (1,84)
    float* __restrict__ out, int n)
{
    __shared__ __align__(16) unsigned char smem[LDS_BYTES];
    unsigned short* feat = (unsigned short*)smem;          // bf16 bits
    float* pooled        = (float*)smem;
    float* hbuf          = (float*)smem;
    float* x30b          = (float*)(smem + X30_OFF);

    const int tid = threadIdx.x;
    const int q   = tid & 3;          // quad lane: which slice of the net
    const int s   = tid >> 2;         // local sample 0..31
    const int gs  = blockIdx.x * SPB + s;
    const bool valid = (gs < n);
    const int gse = valid ? gs : 0;

    const int st = state[gse];
    const int dd = des[gse];
    const int ai = act[gse];

    // ---- Gather (split by position: p = q, q+4, q+8) ----
    // NEW_INDEX = [7,0,1,6,8,2,5,4,3] packed as nibbles (LSB = p0)
    const unsigned long long NIDX = 0x345286107ULL;
    unsigned short* fb16 = feat + s * FEAT_STR;
#pragma unroll
    for (int pp = 0; pp < 3; ++pp) {
        const int p = q + 4 * pp;
        if (p <= 8) {
            const int a  = (int)((NIDX >> (4 * p)) & 15ULL);
            const int na = asp_g[st * 9 + a];
            const float m = (float)pmp_g[st * 9 + a];
            const float4* pf = (const float4*)(path_feature + ((size_t)na * DDIM + dd) * PFN);
            const float4 v0 = pf[0], v1 = pf[1], v2 = pf[2];
            const float4* lf = (const float4*)(link_feature + (size_t)na * LFN);
            const float4 u0 = lf[0], u1 = lf[1];
            unsigned short bv[21];
            bv[0]=f2bf(v0.x); bv[1]=f2bf(v0.y); bv[2]=f2bf(v0.z); bv[3]=f2bf(v0.w);
            bv[4]=f2bf(v1.x); bv[5]=f2bf(v1.y); bv[6]=f2bf(v1.z); bv[7]=f2bf(v1.w);
            bv[8]=f2bf(v2.x); bv[9]=f2bf(v2.y); bv[10]=f2bf(v2.z); bv[11]=f2bf(v2.w);
            bv[12]=f2bf(u0.x); bv[13]=f2bf(u0.y); bv[14]=f2bf(u0.z); bv[15]=f2bf(u0.w);
            bv[16]=f2bf(u1.x); bv[17]=f2bf(u1.y); bv[18]=f2bf(u1.z); bv[19]=f2bf(u1.w);
            bv[20]=f2bf(m);
            unsigned int* dst = (unsigned int*)(fb16 + p * FEAT_PSTR); // 4B aligned
#pragma unroll
            for (int k = 0; k < 10; ++k)
                dst[k] = (unsigned int)bv[2*k] | ((unsigned int)bv[2*k+1] << 16);
            ((unsigned short*)dst)[20] = bv[20];
        }
    }
    __syncthreads();

    // ---- conv1 (pad=1): this thread computes oc in [5q, 5q+5) ----
    const int oc0 = q * 5;
    float o[5][9];
#pragma unroll
    for (int c = 0; c < 5; ++c) {
        const float bb = b1[oc0 + c];
#pragma unroll
        for (int p = 0; p < 9; ++p) o[c][p] = bb;
    }

#pragma unroll 3
    for (int ic = 0; ic < ICH; ++ic) {
        float fv[9];
#pragma unroll
        for (int p = 0; p < 9; ++p)
            fv[p] = bf2f(fb16[p * FEAT_PSTR + ic]);
#pragma unroll
        for (int c = 0; c < 5; ++c) {
            const float* w = w1 + ((oc0 + c) * ICH + ic) * 9;
#pragma unroll
            for (int t = 0; t < 9; ++t) {
                const int ky = t / 3 - 1, kx = t % 3 - 1;
                const float wv = w[t];
#pragma unroll
                for (int y = 0; y < 3; ++y) {
                    const int iy = y + ky;
                    if (iy < 0 || iy > 2) continue;
#pragma unroll
                    for (int x = 0; x < 3; ++x) {
                        const int ix = x + kx;
                        if (ix < 0 || ix > 2) continue;
                        o[c][y * 3 + x] = fmaf(wv, fv[iy * 3 + ix], o[c][y * 3 + x]);
                    }
                }
            }
        }
    }

    // ---- lrelu + 2x2/s1 maxpool -> pl[5][4] ----
    float pl[5][4];
#pragma unroll
    for (int c = 0; c < 5; ++c) {
        float v[9];
#pragma unroll
        for (int p = 0; p < 9; ++p) v[p] = lrelu(o[c][p]);
        pl[c][0] = fmaxf(fmaxf(v[0], v[1]), fmaxf(v[3], v[4]));
        pl[c][1] = fmaxf(fmaxf(v[1], v[2]), fmaxf(v[4], v[5]));
        pl[c][2] = fmaxf(fmaxf(v[3], v[4]), fmaxf(v[6], v[7]));
        pl[c][3] = fmaxf(fmaxf(v[4], v[5]), fmaxf(v[7], v[8]));
    }

    __syncthreads();   // all feat reads done before pooled overwrites region A
#pragma unroll
    for (int c = 0; c < 5; ++c)
        *(float4*)(pooled + s * POOL_STR + (oc0 + c) * 4) =
            make_float4(pl[c][0], pl[c][1], pl[c][2], pl[c][3]);
    __syncthreads();

    // ---- conv2: this thread computes j = q, q+4, ... (<30) ----
    float acc2[8];
#pragma unroll
    for (int jj = 0; jj < 8; ++jj) {
        const int j = q + 4 * jj;
        acc2[jj] = (j < 30) ? b2[j] : 0.0f;
    }
#pragma unroll 2
    for (int oc = 0; oc < 20; ++oc) {
        const float4 p4 = *(const float4*)(pooled + s * POOL_STR + oc * 4);
#pragma unroll
        for (int jj = 0; jj < 8; ++jj) {
            const int j = q + 4 * jj;
            if (j < 30) {
                const float4 w4 = *(const float4*)(w2 + j * 80 + oc * 4);
                acc2[jj] += w4.x * p4.x + w4.y * p4.y + w4.z * p4.z + w4.w * p4.w;
            }
        }
    }
    // x30 region is disjoint from pooled: no barrier needed before writes
#pragma unroll
    for (int jj = 0; jj < 8; ++jj) {
        const int j = q + 4 * jj;
        if (j < 30) x30b[s * X30_STR + j] = lrelu(acc2[jj]);
    }
    __syncthreads();

    // ---- fc1: this thread computes h[j], j = q + 4*jj, jj=0..29 ----
    float xa[30];
    {
        const float4* xp = (const float4*)(x30b + s * X30_STR);
#pragma unroll
        for (int kk = 0; kk < 7; ++kk) {
            const float4 v = xp[kk];
            xa[4*kk+0] = v.x; xa[4*kk+1] = v.y; xa[4*kk+2] = v.z; xa[4*kk+3] = v.w;
        }
        xa[28] = x30b[s * X30_STR + 28];
        xa[29] = x30b[s * X30_STR + 29];
    }
#pragma unroll 2
    for (int jj = 0; jj < 30; ++jj) {
        const int j = q + 4 * jj;
        const float2* wp = (const float2*)(fw1 + (size_t)j * 38);  // 8B aligned
        float acc = fb1[j] + fw1[(size_t)j * 38 + 30 + ai];        // one-hot(act)
#pragma unroll
        for (int kk = 0; kk < 15; ++kk) {
            const float2 wv = wp[kk];
            acc = fmaf(wv.x, xa[2*kk], acc);
            acc = fmaf(wv.y, xa[2*kk+1], acc);
        }
        hbuf[s * H_STR + j] = lrelu(acc);   // region A (feat/pooled dead)
    }
    __syncthreads();

    // ---- fc2: this thread computes acc3[i], i = 21q + ii ----
    const int i0 = q * 21;
    float acc3[21];
#pragma unroll
    for (int ii = 0; ii < 21; ++ii) acc3[ii] = fb2[i0 + ii];

    const float* fw2q = fw2 + (size_t)i0 * 120;
#pragma unroll 1
    for (int jb = 0; jb < 30; ++jb) {
        const float4 h4 = *(const float4*)(hbuf + s * H_STR + jb * 4);
#pragma unroll
        for (int ii = 0; ii < 21; ++ii) {
            const float4 w4 = *(const float4*)(fw2q + (size_t)ii * 120 + jb * 4);
            acc3[ii] += w4.x * h4.x + w4.y * h4.y + w4.z * h4.z + w4.w * h4.w;
        }
    }

    // ---- fc3 + quad reduction + sigmoid ----
    float z = 0.0f;
#pragma unroll
    for (int ii = 0; ii < 21; ++ii)
        z = fmaf(fw3[i0 + ii], lrelu(acc3[ii]), z);
    z += __shfl_xor(z, 1);
    z += __shfl_xor(z, 2);

    if (valid && q == 0)
        out[gs] = 1.0f / (1.0f + __expf(-(z + fb3[0])));
}

extern "C" void kernel_launch(void* const* d_in, const int* in_sizes, int n_in,
                              void* d_out, int out_size, void* d_ws, size_t ws_size,
                              hipStream_t stream) {
    const int*   state = (const int*)d_in[0];
    const int*   des   = (const int*)d_in[1];
    const int*   act   = (const int*)d_in[2];
    const int*   asp   = (const int*)d_in[3];
    const int*   pmp   = (const int*)d_in[4];
    const float* pathf = (const float*)d_in[5];
    const float* linkf = (const float*)d_in[6];
    const float* w1    = (const float*)d_in[7];
    const float* b1    = (const float*)d_in[8];
    const float* w2    = (const float*)d_in[9];
    const float* b2    = (const float*)d_in[10];
    const float* fw1   = (const float*)d_in[11];
    const float* fb1   = (const float*)d_in[12];
    const float* fw2   = (const float*)d_in[13];
    const float* fb2   = (const float*)d_in[14];
    const float* fw3   = (const float*)d_in[15];
    const float* fb3   = (const float*)d_in[16];

    const int n = in_sizes[0];
    dim3 grid((n + SPB - 1) / SPB), block(TPB);
    hipLaunchKernelGGL(disc_kernel, grid, block, 0, stream,
                       state, des, act, asp, pmp, pathf, linkf,
                       w1, b1, w2, b2, fw1, fb1, fw2, fb2, fw3, fb3,
                       (float*)d_out, n);
}

// Round 3
// 809.216 us; speedup vs baseline: 1.0846x; 1.0846x over previous
//
#include <hip/hip_runtime.h>
#include <hip/hip_bf16.h>
#include <math.h>

#define DDIM 300
#define PFN  12
#define LFN  8
#define ICH  21
#define TPB  128
#define SPB  32          // samples per block (4 threads each)

// LDS element strides (per sample)
#define FEAT_PSTR 22                 // bf16 per position (21 used + 1 pad -> 4B align)
#define FEAT_STR  (9 * FEAT_PSTR)    // 198 bf16 = 99 dwords (odd -> bank spread)
#define POOL_STR  84                 // dwords; bank stride 20 -> only free 2-way (s, s+8)
#define X30_STR   36                 // dwords; bank stride 4  -> free 2-way
#define H_STR     124                // dwords; bank stride 28 -> free 2-way (was 120: 4-way!)
// Overlay layout (bytes):
//   region A @0     : feat  (32*396  = 12672)  gather -> conv1
//   region A @0     : pooled(32*336  = 10752)  pool   -> conv2
//   region A @0     : h     (32*496  = 15872)  fc1    -> fc2
//   region B @15872 : x30   (32*144  =  4608)  conv2  -> fc1
#define X30_OFF   15872
#define LDS_BYTES (X30_OFF + SPB * X30_STR * 4)   // 20480 B -> 8 blocks/CU = 160KiB exactly

__device__ __forceinline__ float lrelu(float v) { return v > 0.0f ? v : 0.2f * v; }

__device__ __forceinline__ unsigned short f2bf(float f) {
    return __builtin_bit_cast(unsigned short, __float2bfloat16(f));
}
__device__ __forceinline__ float bf2f(unsigned short u) {
    return __builtin_bit_cast(float, (unsigned int)u << 16);
}

// NOTE: __launch_bounds__(128,4) was mistranslated to an 8-waves/EU target
// (VGPR capped at 64 -> 120MB of scratch spills, R2 regression). Use the
// LLVM attribute directly: waves_per_eu(4) == VGPR cap 128, fits ~85-reg peak.
__attribute__((amdgpu_flat_work_group_size(TPB, TPB), amdgpu_waves_per_eu(4, 8)))
__global__ void disc_kernel(
    const int* __restrict__ state, const int* __restrict__ des,
    const int* __restrict__ act,
    const int* __restrict__ asp_g,   // (S,9)
    const int* __restrict__ pmp_g,   // (S,9)
    const float* __restrict__ path_feature,  // (S,D,12)
    const float* __restrict__ link_feature,  // (S,8)
    const float* __restrict__ w1, const float* __restrict__ b1,   // (20,21,3,3)
    const float* __restrict__ w2, const float* __restrict__ b2,   // (30,20,2,2)
    const float* __restrict__ fw1, const float* __restrict__ fb1, // (120,38)
    const float* __restrict__ fw2, const float* __restrict__ fb2, // (84,120)
    const float* __restrict__ fw3, const float* __restrict__ fb3, // (1,84)
    float* __restrict__ out, int n)
{
    __shared__ __align__(16) unsigned char smem[LDS_BYTES];
    unsigned short* feat = (unsigned short*)smem;          // bf16 bits
    float* pooled        = (float*)smem;
    float* hbuf          = (float*)smem;
    float* x30b          = (float*)(smem + X30_OFF);

    const int tid = threadIdx.x;
    const int q   = tid & 3;          // quad lane: which slice of the net
    const int s   = tid >> 2;         // local sample 0..31
    const int gs  = blockIdx.x * SPB + s;
    const bool valid = (gs < n);
    const int gse = valid ? gs : 0;

    const int st = state[gse];
    const int dd = des[gse];
    const int ai = act[gse];

    // ---- Gather (split by position: p = q, q+4, q+8) ----
    // NEW_INDEX = [7,0,1,6,8,2,5,4,3] packed as nibbles (LSB = p0)
    const unsigned long long NIDX = 0x345286107ULL;
    unsigned short* fb16 = feat + s * FEAT_STR;
#pragma unroll
    for (int pp = 0; pp < 3; ++pp) {
        const int p = q + 4 * pp;
        if (p <= 8) {
            const int a  = (int)((NIDX >> (4 * p)) & 15ULL);
            const int na = asp_g[st * 9 + a];
            const float m = (float)pmp_g[st * 9 + a];
            const float4* pf = (const float4*)(path_feature + ((size_t)na * DDIM + dd) * PFN);
            const float4 v0 = pf[0], v1 = pf[1], v2 = pf[2];
            const float4* lf = (const float4*)(link_feature + (size_t)na * LFN);
            const float4 u0 = lf[0], u1 = lf[1];
            unsigned int* dst = (unsigned int*)(fb16 + p * FEAT_PSTR); // 4B aligned
            dst[0] = (unsigned int)f2bf(v0.x) | ((unsigned int)f2bf(v0.y) << 16);
            dst[1] = (unsigned int)f2bf(v0.z) | ((unsigned int)f2bf(v0.w) << 16);
            dst[2] = (unsigned int)f2bf(v1.x) | ((unsigned int)f2bf(v1.y) << 16);
            dst[3] = (unsigned int)f2bf(v1.z) | ((unsigned int)f2bf(v1.w) << 16);
            dst[4] = (unsigned int)f2bf(v2.x) | ((unsigned int)f2bf(v2.y) << 16);
            dst[5] = (unsigned int)f2bf(v2.z) | ((unsigned int)f2bf(v2.w) << 16);
            dst[6] = (unsigned int)f2bf(u0.x) | ((unsigned int)f2bf(u0.y) << 16);
            dst[7] = (unsigned int)f2bf(u0.z) | ((unsigned int)f2bf(u0.w) << 16);
            dst[8] = (unsigned int)f2bf(u1.x) | ((unsigned int)f2bf(u1.y) << 16);
            dst[9] = (unsigned int)f2bf(u1.z) | ((unsigned int)f2bf(u1.w) << 16);
            ((unsigned short*)dst)[20] = f2bf(m);
        }
    }
    __syncthreads();

    // ---- conv1 (pad=1): this thread computes oc in [5q, 5q+5) ----
    const int oc0 = q * 5;
    float o[5][9];
#pragma unroll
    for (int c = 0; c < 5; ++c) {
        const float bb = b1[oc0 + c];
#pragma unroll
        for (int p = 0; p < 9; ++p) o[c][p] = bb;
    }

#pragma unroll 1    // rolled: keeps peak VGPR pressure under the 128 cap
    for (int ic = 0; ic < ICH; ++ic) {
        float fv[9];
#pragma unroll
        for (int p = 0; p < 9; ++p)
            fv[p] = bf2f(fb16[p * FEAT_PSTR + ic]);
#pragma unroll
        for (int c = 0; c < 5; ++c) {
            const float* w = w1 + ((oc0 + c) * ICH + ic) * 9;
#pragma unroll
            for (int t = 0; t < 9; ++t) {
                const int ky = t / 3 - 1, kx = t % 3 - 1;
                const float wv = w[t];
#pragma unroll
                for (int y = 0; y < 3; ++y) {
                    const int iy = y + ky;
                    if (iy < 0 || iy > 2) continue;
#pragma unroll
                    for (int x = 0; x < 3; ++x) {
                        const int ix = x + kx;
                        if (ix < 0 || ix > 2) continue;
                        o[c][y * 3 + x] = fmaf(wv, fv[iy * 3 + ix], o[c][y * 3 + x]);
                    }
                }
            }
        }
    }

    // ---- lrelu + 2x2/s1 maxpool -> pl[5][4] ----
    float pl[5][4];
#pragma unroll
    for (int c = 0; c < 5; ++c) {
        float v[9];
#pragma unroll
        for (int p = 0; p < 9; ++p) v[p] = lrelu(o[c][p]);
        pl[c][0] = fmaxf(fmaxf(v[0], v[1]), fmaxf(v[3], v[4]));
        pl[c][1] = fmaxf(fmaxf(v[1], v[2]), fmaxf(v[4], v[5]));
        pl[c][2] = fmaxf(fmaxf(v[3], v[4]), fmaxf(v[6], v[7]));
        pl[c][3] = fmaxf(fmaxf(v[4], v[5]), fmaxf(v[7], v[8]));
    }

    __syncthreads();   // all feat reads done before pooled overwrites region A
#pragma unroll
    for (int c = 0; c < 5; ++c)
        *(float4*)(pooled + s * POOL_STR + (oc0 + c) * 4) =
            make_float4(pl[c][0], pl[c][1], pl[c][2], pl[c][3]);
    __syncthreads();

    // ---- conv2: this thread computes j = q, q+4, ... (<30) ----
    float acc2[8];
#pragma unroll
    for (int jj = 0; jj < 8; ++jj) {
        const int j = q + 4 * jj;
        acc2[jj] = (j < 30) ? b2[j] : 0.0f;
    }
#pragma unroll 2
    for (int oc = 0; oc < 20; ++oc) {
        const float4 p4 = *(const float4*)(pooled + s * POOL_STR + oc * 4);
#pragma unroll
        for (int jj = 0; jj < 8; ++jj) {
            const int j = q + 4 * jj;
            if (j < 30) {
                const float4 w4 = *(const float4*)(w2 + j * 80 + oc * 4);
                acc2[jj] += w4.x * p4.x + w4.y * p4.y + w4.z * p4.z + w4.w * p4.w;
            }
        }
    }
    // x30 region is disjoint from pooled: no barrier needed before writes
#pragma unroll
    for (int jj = 0; jj < 8; ++jj) {
        const int j = q + 4 * jj;
        if (j < 30) x30b[s * X30_STR + j] = lrelu(acc2[jj]);
    }
    __syncthreads();

    // ---- fc1: this thread computes h[j], j = q + 4*jj, jj=0..29 ----
    float xa[30];
    {
        const float4* xp = (const float4*)(x30b + s * X30_STR);
#pragma unroll
        for (int kk = 0; kk < 7; ++kk) {
            const float4 v = xp[kk];
            xa[4*kk+0] = v.x; xa[4*kk+1] = v.y; xa[4*kk+2] = v.z; xa[4*kk+3] = v.w;
        }
        xa[28] = x30b[s * X30_STR + 28];
        xa[29] = x30b[s * X30_STR + 29];
    }
#pragma unroll 2
    for (int jj = 0; jj < 30; ++jj) {
        const int j = q + 4 * jj;
        const float2* wp = (const float2*)(fw1 + (size_t)j * 38);  // 8B aligned
        float acc = fb1[j] + fw1[(size_t)j * 38 + 30 + ai];        // one-hot(act)
#pragma unroll
        for (int kk = 0; kk < 15; ++kk) {
            const float2 wv = wp[kk];
            acc = fmaf(wv.x, xa[2*kk], acc);
            acc = fmaf(wv.y, xa[2*kk+1], acc);
        }
        hbuf[s * H_STR + j] = lrelu(acc);   // region A (feat/pooled dead)
    }
    __syncthreads();

    // ---- fc2: this thread computes acc3[i], i = 21q + ii ----
    const int i0 = q * 21;
    float acc3[21];
#pragma unroll
    for (int ii = 0; ii < 21; ++ii) acc3[ii] = fb2[i0 + ii];

    const float* fw2q = fw2 + (size_t)i0 * 120;
#pragma unroll 1
    for (int jb = 0; jb < 30; ++jb) {
        const float4 h4 = *(const float4*)(hbuf + s * H_STR + jb * 4);
#pragma unroll
        for (int ii = 0; ii < 21; ++ii) {
            const float4 w4 = *(const float4*)(fw2q + (size_t)ii * 120 + jb * 4);
            acc3[ii] += w4.x * h4.x + w4.y * h4.y + w4.z * h4.z + w4.w * h4.w;
        }
    }

    // ---- fc3 + quad reduction + sigmoid ----
    float z = 0.0f;
#pragma unroll
    for (int ii = 0; ii < 21; ++ii)
        z = fmaf(fw3[i0 + ii], lrelu(acc3[ii]), z);
    z += __shfl_xor(z, 1);
    z += __shfl_xor(z, 2);

    if (valid && q == 0)
        out[gs] = 1.0f / (1.0f + __expf(-(z + fb3[0])));
}

extern "C" void kernel_launch(void* const* d_in, const int* in_sizes, int n_in,
                              void* d_out, int out_size, void* d_ws, size_t ws_size,
                              hipStream_t stream) {
    const int*   state = (const int*)d_in[0];
    const int*   des   = (const int*)d_in[1];
    const int*   act   = (const int*)d_in[2];
    const int*   asp   = (const int*)d_in[3];
    const int*   pmp   = (const int*)d_in[4];
    const float* pathf = (const float*)d_in[5];
    const float* linkf = (const float*)d_in[6];
    const float* w1    = (const float*)d_in[7];
    const float* b1    = (const float*)d_in[8];
    const float* w2    = (const float*)d_in[9];
    const float* b2    = (const float*)d_in[10];
    const float* fw1   = (const float*)d_in[11];
    const float* fb1   = (const float*)d_in[12];
    const float* fw2   = (const float*)d_in[13];
    const float* fb2   = (const float*)d_in[14];
    const float* fw3   = (const float*)d_in[15];
    const float* fb3   = (const float*)d_in[16];

    const int n = in_sizes[0];
    dim3 grid((n + SPB - 1) / SPB), block(TPB);
    hipLaunchKernelGGL(disc_kernel, grid, block, 0, stream,
                       state, des, act, asp, pmp, pathf, linkf,
                       w1, b1, w2, b2, fw1, fb1, fw2, fb2, fw3, fb3,
                       (float*)d_out, n);
}